// Round 4
// baseline (143.384 us; speedup 1.0000x reference)
//
#include <hip/hip_runtime.h>
#include <math.h>

#define BATCH 2048
#define FEAT  2048
#define SIXB  6

// ---------------------------------------------------------------------------
// Theory (round 3): the graded numpy reference carries FLOAT32 activations
// between layers and computes sigmoid as the f32 CHAIN
//     e = f32(np.exp(-v));  s = 1.0f / (1.0f + e)
// (two roundings). Round 1 used the single-rounded f32 sigmoid and round 3
// used f64 -- both track the EXACT sigmoid, and both produced the bit-
// identical absmax 2.632812 (same ~2-4 boundary flips vs the chain-rounded
// ref, cascading through LUT indices). Fix: replicate the f32 chain exactly.
//   - exp: RN32(exp_f64(-v)) == correctly-rounded f32 exp (double-rounding
//     hazard ~2^-29, negligible)
//   - 1.0f + e, 1.0f / (...): plain f32 IEEE ops (no fma pattern; hipcc f32
//     division at -O3 is IEEE-correct)
//   - layer-1 transform: (v + 1.0f) * 0.5f  -- the same f32 chain numpy runs
//   - comparisons in f32
// ---------------------------------------------------------------------------
template<bool TRANSFORM_IN, bool SIGMOID_OUT>
__global__ __launch_bounds__(256) void lut_layer_f32chain(
    const float* __restrict__ x, const float* __restrict__ r,
    const int* __restrict__ connect, const float* __restrict__ lut,
    float* __restrict__ out)
{
    __shared__ float xs[FEAT];   // 8 KiB: one activation row
    const int b   = blockIdx.x;
    const int tid = threadIdx.x;

    // Stage x row -> LDS (coalesced float4).
    const float4* xrow = reinterpret_cast<const float4*>(x + (size_t)b * FEAT);
    float4* xs4 = reinterpret_cast<float4*>(xs);
    for (int i = tid; i < FEAT / 4; i += 256) {
        float4 v = xrow[i];
        if (TRANSFORM_IN) {
            v.x = (v.x + 1.0f) * 0.5f;
            v.y = (v.y + 1.0f) * 0.5f;
            v.z = (v.z + 1.0f) * 0.5f;
            v.w = (v.w + 1.0f) * 0.5f;
        }
        xs4[i] = v;
    }
    __syncthreads();

    for (int f0 = 0; f0 < FEAT; f0 += 256) {
        const int f = f0 + tid;

        // connect[f, 0..5]: int32, 24 B at 8 B alignment; L2-resident.
        const int2* cp = reinterpret_cast<const int2*>(connect + (size_t)f * SIXB);
        const int2 c01 = cp[0], c23 = cp[1], c45 = cp[2];

        // r[b, f, 0..5]: wave covers contiguous 1536 B.
        const float2* rp = reinterpret_cast<const float2*>(
            r + ((size_t)b * FEAT + f) * SIXB);
        const float2 r01 = rp[0], r23 = rp[1], r45 = rp[2];

        int idx = 0;
        idx |= (xs[c01.x] >= r01.x) ? 1  : 0;
        idx |= (xs[c01.y] >= r01.y) ? 2  : 0;
        idx |= (xs[c23.x] >= r23.x) ? 4  : 0;
        idx |= (xs[c23.y] >= r23.y) ? 8  : 0;
        idx |= (xs[c45.x] >= r45.x) ? 16 : 0;
        idx |= (xs[c45.y] >= r45.y) ? 32 : 0;

        float v = lut[(size_t)f * 64 + idx];
        if (SIGMOID_OUT) {
            // f32 CHAIN sigmoid, matching numpy's 1/(1+np.exp(-v)) on f32:
            float e = (float)exp(-(double)v);   // correctly-rounded f32 exp
            v = 1.0f / (1.0f + e);              // f32 IEEE add + div
        }
        out[(size_t)b * FEAT + f] = v;
    }
}

extern "C" void kernel_launch(void* const* d_in, const int* in_sizes, int n_in,
                              void* d_out, int out_size, void* d_ws, size_t ws_size,
                              hipStream_t stream) {
    const float* inputs = (const float*)d_in[0];
    const float* r1     = (const float*)d_in[1];
    const float* r2     = (const float*)d_in[2];
    const float* r3     = (const float*)d_in[3];
    const float* lut1   = (const float*)d_in[4];
    const float* lut2   = (const float*)d_in[5];
    const float* lut3   = (const float*)d_in[6];
    const int*   c1     = (const int*)d_in[7];
    const int*   c2     = (const int*)d_in[8];
    const int*   c3     = (const int*)d_in[9];
    float* out = (float*)d_out;

    const size_t n = (size_t)BATCH * FEAT;
    float* ws1 = (float*)d_ws;        // [BATCH, FEAT] f32 activations, layer 1
    float* ws2 = ws1 + n;             // [BATCH, FEAT] f32 activations, layer 2

    dim3 grid(BATCH), block(256);
    lut_layer_f32chain<true,  true ><<<grid, block, 0, stream>>>(inputs, r1, c1, lut1, ws1);
    lut_layer_f32chain<false, true ><<<grid, block, 0, stream>>>(ws1,    r2, c2, lut2, ws2);
    lut_layer_f32chain<false, false><<<grid, block, 0, stream>>>(ws2,    r3, c3, lut3, out);
}

// Round 5
// 139.906 us; speedup vs baseline: 1.0249x; 1.0249x over previous
//
#include <hip/hip_runtime.h>
#include <math.h>

#define BATCH 2048
#define FEAT  2048
#define TILE  256
#define NT    (FEAT / TILE)   // 8 tiles per layer

// ---------------------------------------------------------------------------
// Fused 3-layer LUT net, one block per batch row.
//
// Round-4 diagnosis: TA/address-divergence bound (~1 lane-addr/cycle/CU).
// The strided r (float2, 24 B lane-stride) and connect (int2) loads cost
// ~64 TA-cycles per wave-instr; 48 of 56 divergent cycles per feature.
// Fix: coalesced float4/int4 staging of each 256-feature tile's r (6 KB)
// and connect (6 KB) into LDS; per-thread reads come from LDS instead.
// The lut gather (64 distinct rows per wave) stays divergent -- intrinsic.
//
// Fusion: block b computes its ENTIRE activation row per layer into LDS
// (xs <-> ys ping-pong), so intermediates never touch HBM and the x-gather
// of the next layer reads LDS. Saves 67 MB traffic + 2 launch tails.
//
// Numerics (locked by round 4, absmax 0.0): f32 chain throughout --
//   layer1 transform: (v + 1.0f) * 0.5f
//   sigmoid:          e = (float)exp(-(double)v);  s = 1.0f / (1.0f + e)
// ---------------------------------------------------------------------------

template<int OUT_MODE>   // 0: sigmoid -> LDS row; 1: raw lut value -> global
__device__ __forceinline__ void lut_layer(
    const float* __restrict__ r, const int* __restrict__ c,
    const float* __restrict__ lut,
    const float* xsrc,          // LDS: source activation row [FEAT]
    float* ydst_lds,            // LDS: dest activation row [FEAT] (OUT_MODE 0)
    float* __restrict__ ydst_g, // global dest (OUT_MODE 1)
    float* sr, int* sc,         // LDS staging: [TILE*6] floats / ints
    int b, int tid)
{
    for (int t = 0; t < NT; ++t) {
        const int f0 = t * TILE;

        __syncthreads();   // prior tile's sr/sc reads (and prior layer) done

        // Coalesced staging: r-tile 1536 floats, c-tile 1536 ints (384 xf4).
        const float4* rg = reinterpret_cast<const float4*>(
            r + ((size_t)b * FEAT + f0) * 6);
        const int4* cg = reinterpret_cast<const int4*>(c + (size_t)f0 * 6);
        float4* sr4 = reinterpret_cast<float4*>(sr);
        int4*   sc4 = reinterpret_cast<int4*>(sc);
        #pragma unroll
        for (int i = tid; i < (TILE * 6) / 4; i += 256) {
            sr4[i] = rg[i];
            sc4[i] = cg[i];
        }

        __syncthreads();   // staging visible

        const int f = f0 + tid;
        const float* rr = sr + tid * 6;
        const int*   cc = sc + tid * 6;

        int idx = 0;
        idx |= (xsrc[cc[0]] >= rr[0]) ? 1  : 0;
        idx |= (xsrc[cc[1]] >= rr[1]) ? 2  : 0;
        idx |= (xsrc[cc[2]] >= rr[2]) ? 4  : 0;
        idx |= (xsrc[cc[3]] >= rr[3]) ? 8  : 0;
        idx |= (xsrc[cc[4]] >= rr[4]) ? 16 : 0;
        idx |= (xsrc[cc[5]] >= rr[5]) ? 32 : 0;

        const float v = lut[(size_t)f * 64 + idx];
        if (OUT_MODE == 0) {
            float e = (float)exp(-(double)v);   // correctly-rounded f32 exp
            ydst_lds[f] = 1.0f / (1.0f + e);    // f32 IEEE chain
        } else {
            ydst_g[(size_t)b * FEAT + f] = v;
        }
    }
}

__global__ __launch_bounds__(256) void fused3_kernel(
    const float* __restrict__ inputs,
    const float* __restrict__ r1, const float* __restrict__ r2,
    const float* __restrict__ r3,
    const float* __restrict__ lut1, const float* __restrict__ lut2,
    const float* __restrict__ lut3,
    const int* __restrict__ c1, const int* __restrict__ c2,
    const int* __restrict__ c3,
    float* __restrict__ out)
{
    __shared__ float xs[FEAT];       // 8 KiB
    __shared__ float ys[FEAT];       // 8 KiB
    __shared__ float sr[TILE * 6];   // 6 KiB
    __shared__ int   sc[TILE * 6];   // 6 KiB   -> 28 KiB total, 5 blocks/CU

    const int b   = blockIdx.x;
    const int tid = threadIdx.x;

    // Stage input row -> xs with the f32 transform (coalesced float4).
    {
        const float4* xrow = reinterpret_cast<const float4*>(
            inputs + (size_t)b * FEAT);
        float4* xs4 = reinterpret_cast<float4*>(xs);
        #pragma unroll
        for (int i = tid; i < FEAT / 4; i += 256) {
            float4 v = xrow[i];
            v.x = (v.x + 1.0f) * 0.5f;
            v.y = (v.y + 1.0f) * 0.5f;
            v.z = (v.z + 1.0f) * 0.5f;
            v.w = (v.w + 1.0f) * 0.5f;
            xs4[i] = v;
        }
    }
    // (tile-0 leading __syncthreads() inside lut_layer covers xs staging)

    lut_layer<0>(r1, c1, lut1, xs, ys, nullptr, sr, sc, b, tid);  // xs -> ys
    lut_layer<0>(r2, c2, lut2, ys, xs, nullptr, sr, sc, b, tid);  // ys -> xs
    lut_layer<1>(r3, c3, lut3, xs, nullptr, out, sr, sc, b, tid); // xs -> out
}

extern "C" void kernel_launch(void* const* d_in, const int* in_sizes, int n_in,
                              void* d_out, int out_size, void* d_ws, size_t ws_size,
                              hipStream_t stream) {
    const float* inputs = (const float*)d_in[0];
    const float* r1     = (const float*)d_in[1];
    const float* r2     = (const float*)d_in[2];
    const float* r3     = (const float*)d_in[3];
    const float* lut1   = (const float*)d_in[4];
    const float* lut2   = (const float*)d_in[5];
    const float* lut3   = (const float*)d_in[6];
    const int*   c1     = (const int*)d_in[7];
    const int*   c2     = (const int*)d_in[8];
    const int*   c3     = (const int*)d_in[9];
    float* out = (float*)d_out;

    fused3_kernel<<<dim3(BATCH), dim3(256), 0, stream>>>(
        inputs, r1, r2, r3, lut1, lut2, lut3, c1, c2, c3, out);
}